// Round 1
// baseline (5376.269 us; speedup 1.0000x reference)
//
#include <hip/hip_runtime.h>

// HSMM forward log-likelihood, B=32, T=8192, K=128, Dmax=128.
// One block per sequence (32 blocks, 512 threads = 8 waves).
// Probability-space recursion with per-step scalar renorm (deferred one step)
// and a per-state gauge psi so ring-buffer entries are write-once.
//
// Thread layout: lane L (0..63), wave w (0..7):
//   j = (L&15) + 16*w   (owned state, 128 total)
//   c = L>>4            (reduction chunk 0..3)
// Per-thread registers:
//   QA[16],QB[16]: ring slots p = 16c+k  and  p = 64+16c+k
//   aA[16],aB[16]: exp(log_A)[i][j] for i = 16c+k and 64+16c+k
//   eA[16],eB[16]: rotating expD window (slot k at step t -> reg [(k-t)&15])
//   lb[16]:        log_B prefetch ring (16 steps ahead)

#define T_LEN 8192
#define KST   128
#define NTHR  512

__global__ __launch_bounds__(NTHR, 2) void hsmm_fwd_kernel(
    const float* __restrict__ logB_all,
    const float* __restrict__ logpi,
    const float* __restrict__ logA,
    const float* __restrict__ logD,
    float* __restrict__ out)
{
  const int tid = threadIdx.x;
  const int L   = tid & 63;
  const int w   = tid >> 6;
  const int jj  = (L & 15) + 16 * w;   // owned state
  const int c   = L >> 4;              // chunk 0..3
  const int b   = blockIdx.x;
  const float* __restrict__ logB = logB_all + (size_t)b * T_LEN * KST;

  __shared__ float expD_t[128][KST];   // [d][j]; row 0 zeroed (stale-slot kill)
  __shared__ float s_lds[2][KST];      // shat exchange, double buffered
  __shared__ float m_lds[2][8];        // per-wave maxes, double buffered
  __shared__ float fin[8];

  // ---- init: transposed expD table (row0 = 0), s/m buffers ----
  for (int idx = tid; idx < 128 * KST; idx += NTHR) {
    int d = idx >> 7, j0 = idx & 127;
    expD_t[d][j0] = (d == 0) ? 0.0f : __expf(logD[j0 * 128 + d]);
  }
  if (tid < KST) s_lds[0][tid] = 0.0f;
  if (tid < 8) { m_lds[0][tid] = 1.0f; m_lds[1][tid] = 1.0f; }

  // ---- per-thread constants ----
  float aA[16], aB[16];
#pragma unroll
  for (int k = 0; k < 16; ++k) {
    aA[k] = __expf(logA[(16 * c + k) * KST + jj]);
    aB[k] = __expf(logA[(64 + 16 * c + k) * KST + jj]);
  }
  const float expD0 = __expf(logD[jj * 128 + 0]);
  const float pexp  = __expf(logpi[jj]);

  float QA[16], QB[16];
#pragma unroll
  for (int k = 0; k < 16; ++k) { QA[k] = 0.0f; QB[k] = 0.0f; }

  __syncthreads();  // expD_t ready

  // expD window init for t=0: slot k -> reg k holds expD[(0 - p)&127]
  float eA[16], eB[16];
#pragma unroll
  for (int k = 0; k < 16; ++k) {
    eA[k] = expD_t[(-(16 * c + k)) & 127][jj];
    eB[k] = expD_t[(-(64 + 16 * c + k)) & 127][jj];
  }

  // log_B prefetch ring
  float lb[16];
#pragma unroll
  for (int u = 0; u < 16; ++u) lb[u] = logB[u * KST + jj];

  float psi  = 1.0f;   // e^{cB[t+1,j] - C_t - gamma_j}
  float Ctot = 0.0f;   // running C (sum of log M)
  float s_keep = 0.0f;

#pragma unroll 1
  for (int t0 = 0; t0 < T_LEN; t0 += 16) {
#pragma unroll
    for (int u = 0; u < 16; ++u) {
      const int t = t0 + u;

      // (1) previous step's global max M (8 wave maxes, broadcast reads)
      float4 mm0 = *(const float4*)&m_lds[u & 1][0];
      float4 mm1 = *(const float4*)&m_lds[u & 1][4];
      float Mp = fmaxf(fmaxf(fmaxf(mm0.x, mm0.y), fmaxf(mm0.z, mm0.w)),
                       fmaxf(fmaxf(mm1.x, mm1.y), fmaxf(mm1.z, mm1.w)));
      float rMp = __builtin_amdgcn_rcpf(Mp);
      Ctot += __logf(Mp);

      // (2) shat(t-1) reads for matvec (quarter-uniform b128 reads)
      const float4* sp = (const float4*)&s_lds[u & 1][0];
      float4 sA0 = sp[4 * c + 0], sA1 = sp[4 * c + 1];
      float4 sA2 = sp[4 * c + 2], sA3 = sp[4 * c + 3];
      float4 sB0 = sp[16 + 4 * c + 0], sB1 = sp[16 + 4 * c + 1];
      float4 sB2 = sp[16 + 4 * c + 2], sB3 = sp[16 + 4 * c + 3];

      // (3) duration dot over ring slots (stale slot has e == 0)
      float dp = 0.0f;
#pragma unroll
      for (int k = 0; k < 16; ++k) {
        dp = fmaf(QA[k], eA[(k - u) & 15], dp);
        dp = fmaf(QB[k], eB[(k - u) & 15], dp);
      }

      // (4) psi update (gauge carries emissions + renorm)
      float expB   = __expf(lb[u]);
      float invpsi = __builtin_amdgcn_rcpf(psi);  // 1/psi_{t-1}
      psi = psi * expB * rMp;

      // (5) matvec partial: chunk [16c,16c+16) and [64+16c, 64+16c+16)
      float mp = 0.0f;
      mp = fmaf(aA[0], sA0.x, mp);  mp = fmaf(aA[1], sA0.y, mp);
      mp = fmaf(aA[2], sA0.z, mp);  mp = fmaf(aA[3], sA0.w, mp);
      mp = fmaf(aA[4], sA1.x, mp);  mp = fmaf(aA[5], sA1.y, mp);
      mp = fmaf(aA[6], sA1.z, mp);  mp = fmaf(aA[7], sA1.w, mp);
      mp = fmaf(aA[8], sA2.x, mp);  mp = fmaf(aA[9], sA2.y, mp);
      mp = fmaf(aA[10], sA2.z, mp); mp = fmaf(aA[11], sA2.w, mp);
      mp = fmaf(aA[12], sA3.x, mp); mp = fmaf(aA[13], sA3.y, mp);
      mp = fmaf(aA[14], sA3.z, mp); mp = fmaf(aA[15], sA3.w, mp);
      mp = fmaf(aB[0], sB0.x, mp);  mp = fmaf(aB[1], sB0.y, mp);
      mp = fmaf(aB[2], sB0.z, mp);  mp = fmaf(aB[3], sB0.w, mp);
      mp = fmaf(aB[4], sB1.x, mp);  mp = fmaf(aB[5], sB1.y, mp);
      mp = fmaf(aB[6], sB1.z, mp);  mp = fmaf(aB[7], sB1.w, mp);
      mp = fmaf(aB[8], sB2.x, mp);  mp = fmaf(aB[9], sB2.y, mp);
      mp = fmaf(aB[10], sB2.z, mp); mp = fmaf(aB[11], sB2.w, mp);
      mp = fmaf(aB[12], sB3.x, mp); mp = fmaf(aB[13], sB3.y, mp);
      mp = fmaf(aB[14], sB3.z, mp); mp = fmaf(aB[15], sB3.w, mp);

      // (6) intra-wave chunk reduction (c lives on lane bits 4,5)
      dp += __shfl_xor(dp, 16); dp += __shfl_xor(dp, 32);
      mp += __shfl_xor(mp, 16); mp += __shfl_xor(mp, 32);

      // (7) insert value: Qins = mv * invpsi  (M factors cancel exactly)
      float Qins = (t == 0) ? pexp : mp * invpsi;

      // (8) shat_t = (dot + Qins*expD[j,0]) * psi_t
      float s = fmaf(Qins, expD0, dp) * psi;

      // (9) ring insert (slot p = t&127; static reg index u)
      if (((t >> 4) & 7) == c)     QA[u] = Qins;
      if (((t >> 4) & 7) == c + 4) QB[u] = Qins;

      // (10) in-wave max over this wave's 16 states (lane bits 0..3)
      float sm = s;
      sm = fmaxf(sm, __shfl_xor(sm, 1));
      sm = fmaxf(sm, __shfl_xor(sm, 2));
      sm = fmaxf(sm, __shfl_xor(sm, 4));
      sm = fmaxf(sm, __shfl_xor(sm, 8));

      // (11) publish to next step's buffers
      if (L == 0) m_lds[(u + 1) & 1][w] = sm;
      if (c == 0) s_lds[(u + 1) & 1][jj] = s;

      // (12) expD window rotation: one fresh value per run
      eA[(-(u + 1)) & 15] = expD_t[(t + 1 - 16 * c) & 127][jj];
      eB[(-(u + 1)) & 15] = expD_t[(t + 1 - 64 - 16 * c) & 127][jj];

      // (13) log_B prefetch 16 ahead (clamped; tail values unused)
      int tn = t + 16; tn = (tn < T_LEN) ? tn : (T_LEN - 1);
      lb[u] = logB[tn * KST + jj];

      // (14) gauge renorm every 16 steps: fold psi_t into Q, reset psi
      if (u == 15) {
#pragma unroll
        for (int k = 0; k < 16; ++k) { QA[k] *= psi; QB[k] *= psi; }
        psi = 1.0f;
      }

      s_keep = s;
      __syncthreads();
    }
  }

  // ---- final: out[b] = C_{T-1} + log sum_j shat_{T-1}[j] ----
  float ssum = s_keep;
  ssum += __shfl_xor(ssum, 1);
  ssum += __shfl_xor(ssum, 2);
  ssum += __shfl_xor(ssum, 4);
  ssum += __shfl_xor(ssum, 8);
  if (L == 0) fin[w] = ssum;
  __syncthreads();
  if (tid == 0) {
    float tot = 0.0f;
#pragma unroll
    for (int i = 0; i < 8; ++i) tot += fin[i];
    out[b] = Ctot + __logf(tot);
  }
}

extern "C" void kernel_launch(void* const* d_in, const int* in_sizes, int n_in,
                              void* d_out, int out_size, void* d_ws, size_t ws_size,
                              hipStream_t stream) {
  const float* logB  = (const float*)d_in[0];
  const float* logpi = (const float*)d_in[1];
  const float* logA  = (const float*)d_in[2];
  const float* logD  = (const float*)d_in[3];
  float* out = (float*)d_out;
  const int B = out_size;  // 32
  hipLaunchKernelGGL(hsmm_fwd_kernel, dim3(B), dim3(NTHR), 0, stream,
                     logB, logpi, logA, logD, out);
}